// Round 2
// baseline (114.199 us; speedup 1.0000x reference)
//
#include <hip/hip_runtime.h>
#include <cstdint>

#define T_SEQ 4096
#define E_DIM 1024
#define N_B   8
#define SC    128      // seq positions per block
#define TILE_P 148     // s0-10 .. s0+137
#define LDS_ST 149     // +1 pad -> conflict-free for scalar reads

constexpr int LW[4] = {2, 8, 12, 6};

// dec_lo
constexpr float DLf[4][12] = {
  {0.7071067811865476f, 0.7071067811865476f, 0,0,0,0,0,0,0,0,0,0},
  {-0.010597401784997278f, 0.032883011666982945f, 0.030841381835986965f, -0.18703481171888114f,
   -0.02798376941698385f, 0.6308807679295904f, 0.7148465705525415f, 0.23037781330885523f, 0,0,0,0},
  {-0.007800708325034148f, 0.0017677118642428036f, 0.04472490177066578f, -0.021060292512300564f,
   -0.07263752278646252f, 0.3379294217276218f, 0.787641141030194f, 0.4910559419267466f,
   -0.048311742585633f, -0.11799011114819057f, 0.0034907120842174702f, 0.015404109327027373f},
  {-0.08838834764831845f, 0.08838834764831845f, 0.7071067811865476f, 0.7071067811865476f,
    0.08838834764831845f, -0.08838834764831845f, 0,0,0,0,0,0},
};
// dec_hi
constexpr float DHf[4][12] = {
  {-0.7071067811865476f, 0.7071067811865476f, 0,0,0,0,0,0,0,0,0,0},
  {-0.23037781330885523f, 0.7148465705525415f, -0.6308807679295904f, -0.02798376941698385f,
    0.18703481171888114f, 0.030841381835986965f, -0.032883011666982945f, -0.010597401784997278f, 0,0,0,0},
  {-0.015404109327027373f, 0.0034907120842174702f, 0.11799011114819057f, -0.048311742585633f,
   -0.4910559419267466f, 0.787641141030194f, -0.3379294217276218f, -0.07263752278646252f,
    0.021060292512300564f, 0.04472490177066578f, -0.0017677118642428036f, -0.007800708325034148f},
  {0,0,-0.7071067811865476f, 0.7071067811865476f, 0,0, 0,0,0,0,0,0},
};
// rec_lo
constexpr float RLf[4][12] = {
  {0.7071067811865476f, 0.7071067811865476f, 0,0,0,0,0,0,0,0,0,0},
  {0.23037781330885523f, 0.7148465705525415f, 0.6308807679295904f, -0.02798376941698385f,
   -0.18703481171888114f, 0.030841381835986965f, 0.032883011666982945f, -0.010597401784997278f, 0,0,0,0},
  {0.015404109327027373f, 0.0034907120842174702f, -0.11799011114819057f, -0.048311742585633f,
   0.4910559419267466f, 0.787641141030194f, 0.3379294217276218f, -0.07263752278646252f,
   -0.021060292512300564f, 0.04472490177066578f, 0.0017677118642428036f, -0.007800708325034148f},
  {0,0,0.7071067811865476f, 0.7071067811865476f, 0,0, 0,0,0,0,0,0},
};
// rec_hi
constexpr float RHf[4][12] = {
  {0.7071067811865476f, -0.7071067811865476f, 0,0,0,0,0,0,0,0,0,0},
  {-0.010597401784997278f, -0.032883011666982945f, 0.030841381835986965f, 0.18703481171888114f,
   -0.02798376941698385f, -0.6308807679295904f, 0.7148465705525415f, -0.23037781330885523f, 0,0,0,0},
  {-0.007800708325034148f, -0.0017677118642428036f, 0.04472490177066578f, 0.021060292512300564f,
   -0.07263752278646252f, -0.3379294217276218f, 0.787641141030194f, -0.4910559419267466f,
   -0.048311742585633f, 0.11799011114819057f, 0.0034907120842174702f, -0.015404109327027373f},
  {-0.08838834764831845f, -0.08838834764831845f, 0.7071067811865476f, -0.7071067811865476f,
    0.08838834764831845f, 0.08838834764831845f, 0,0,0,0,0,0},
};

template <int W>
__device__ __forceinline__ void wavelet_accum(const float (&xw)[52], float (&acc)[32],
                                              float la, float ld, float g2, float wgt) {
  constexpr int L  = LW[W];
  constexpr int KT = L / 2 + 15;
#pragma unroll
  for (int kk = 0; kk < KT; ++kk) {
    float lo = 0.f, hi = 0.f;
#pragma unroll
    for (int m = 0; m < L; ++m) {
      const float xv = xw[2 * kk + 11 - m];
      if (DLf[W][m] != 0.0f) lo = fmaf(DLf[W][m], xv, lo);
      if (DHf[W][m] != 0.0f) hi = fmaf(DHf[W][m], xv, hi);
    }
    const float loS = g2 * copysignf(fmaxf(fabsf(lo) - la, 0.f), lo);
    const float hiS = g2 * copysignf(fmaxf(fabsf(hi) - ld, 0.f), hi);
#pragma unroll
    for (int m = 0; m < L; ++m) {
      const int j = 2 * kk + m + 2 - L;   // compile-time after unroll
      if (j >= 0 && j < 32) {
        float c = 0.f;
        if (RLf[W][m] != 0.0f) c = fmaf(loS, RLf[W][m], c);
        if (RHf[W][m] != 0.0f) c = fmaf(hiS, RHf[W][m], c);
        acc[j] = fmaf(wgt, c, acc[j]);
      }
    }
  }
}

__global__ __launch_bounds__(256, 3) void wlm_k1(
    const float* __restrict__ x,
    const float* __restrict__ la_, const float* __restrict__ ld_,
    const float* __restrict__ lg_, const float* __restrict__ th_,
    const float* __restrict__ bl_, float* __restrict__ y) {
  __shared__ float xs[64][LDS_ST];  // 38,144 B -> 4 blocks/CU (LDS-limited)

  const int tid  = threadIdx.x;
  const int lane = tid & 63;
  const int wave = tid >> 6;
  const int s0 = blockIdx.x * SC;
  const int e0 = blockIdx.y * 64;
  const int b  = blockIdx.z;

  // ---- stage x tile [s0-10, s0+138) x 64 channels, reflect at borders ----
  {
    const int ch4 = (tid & 15) * 4;
#pragma unroll
    for (int it = 0; it < 10; ++it) {
      const int pos = (tid >> 4) + it * 16;
      if (pos < TILE_P) {
        int g = s0 - 10 + pos;
        g = (g < 0) ? -g : g;
        g = (g >= T_SEQ) ? (2 * T_SEQ - 2 - g) : g;
        const float4 v = *reinterpret_cast<const float4*>(
            &x[((size_t)b * T_SEQ + g) * E_DIM + e0 + ch4]);
        xs[ch4 + 0][pos] = v.x;
        xs[ch4 + 1][pos] = v.y;
        xs[ch4 + 2][pos] = v.z;
        xs[ch4 + 3][pos] = v.w;
      }
    }
  }

  // ---- per-channel params ----
  const int e = e0 + lane;
  const float la = la_[e];
  const float ld = ld_[e];
  const float lg = lg_[e];
  const float th = th_[e];
  const float sp = fmaxf(lg, 0.f) + log1pf(expf(-fabsf(lg)));  // softplus
  const float g2 = (sp + 1e-6f) * cosf(th);

  const float b0 = bl_[0], b1 = bl_[1], b2 = bl_[2], b3 = bl_[3];
  const float mx = fmaxf(fmaxf(b0, b1), fmaxf(b2, b3));
  float w0 = expf(b0 - mx), w1 = expf(b1 - mx), w2 = expf(b2 - mx), w3 = expf(b3 - mx);
  const float wsum = w0 + w1 + w2 + w3;
  w0 /= wsum; w1 /= wsum; w2 /= wsum; w3 /= wsum;

  __syncthreads();

  // ---- per-thread register window: x_ref[sA-10 .. sA+41] ----
  float xw[52];
#pragma unroll
  for (int i = 0; i < 52; ++i) xw[i] = xs[lane][wave * 32 + i];
  // Pin the window into VGPRs: without this the compiler rematerializes
  // every use as a fresh ds_read_b32 (~544 LDS reads/thread, R1 showed
  // VGPR_Count=56 -> LDS-issue-bound at ~105us).
#pragma unroll
  for (int i = 0; i < 52; ++i) asm volatile("" : "+v"(xw[i]));

  float acc[32];
#pragma unroll
  for (int j = 0; j < 32; ++j) acc[j] = 0.f;

  wavelet_accum<0>(xw, acc, la, ld, g2, w0);
  wavelet_accum<1>(xw, acc, la, ld, g2, w1);
  wavelet_accum<2>(xw, acc, la, ld, g2, w2);
  wavelet_accum<3>(xw, acc, la, ld, g2, w3);

  // ---- y = x + sum_i w_i * rec_i ----
  const int sA = s0 + wave * 32;
#pragma unroll
  for (int j = 0; j < 32; ++j) {
    y[((size_t)b * T_SEQ + sA + j) * E_DIM + e] = xw[j + 10] + acc[j];
  }
}

__global__ __launch_bounds__(256) void wlm_k2(float* __restrict__ y,
                                              const float* __restrict__ w,
                                              const float* __restrict__ bias) {
  const int token = blockIdx.x;
  const int tid = threadIdx.x;
  float* row = y + (size_t)token * E_DIM;

  float4 v = *reinterpret_cast<const float4*>(&row[tid * 4]);
  float s  = v.x + v.y + v.z + v.w;
  float sq = v.x * v.x + v.y * v.y + v.z * v.z + v.w * v.w;
#pragma unroll
  for (int off = 32; off; off >>= 1) {
    s  += __shfl_down(s, off);
    sq += __shfl_down(sq, off);
  }
  __shared__ float ps[4], pq[4], stat[2];
  const int wave = tid >> 6, lane = tid & 63;
  if (lane == 0) { ps[wave] = s; pq[wave] = sq; }
  __syncthreads();
  if (tid == 0) {
    const float S1 = ps[0] + ps[1] + ps[2] + ps[3];
    const float S2 = pq[0] + pq[1] + pq[2] + pq[3];
    const float mu = S1 * (1.f / E_DIM);
    const float var = S2 * (1.f / E_DIM) - mu * mu;
    stat[0] = mu;
    stat[1] = rsqrtf(var + 1e-5f);
  }
  __syncthreads();
  const float mu = stat[0], rstd = stat[1];
  const float4 wv = *reinterpret_cast<const float4*>(&w[tid * 4]);
  const float4 bv = *reinterpret_cast<const float4*>(&bias[tid * 4]);
  float4 o;
  o.x = (v.x - mu) * rstd * wv.x + bv.x;
  o.y = (v.y - mu) * rstd * wv.y + bv.y;
  o.z = (v.z - mu) * rstd * wv.z + bv.z;
  o.w = (v.w - mu) * rstd * wv.w + bv.w;
  *reinterpret_cast<float4*>(&row[tid * 4]) = o;
}

extern "C" void kernel_launch(void* const* d_in, const int* in_sizes, int n_in,
                              void* d_out, int out_size, void* d_ws, size_t ws_size,
                              hipStream_t stream) {
  const float* x   = (const float*)d_in[0];
  const float* la  = (const float*)d_in[1];
  const float* ldt = (const float*)d_in[2];
  const float* lg  = (const float*)d_in[3];
  const float* th  = (const float*)d_in[4];
  const float* bl  = (const float*)d_in[5];
  const float* lnw = (const float*)d_in[6];
  const float* lnb = (const float*)d_in[7];
  float* out = (float*)d_out;

  dim3 g1(T_SEQ / SC, E_DIM / 64, N_B);  // (32, 16, 8)
  wlm_k1<<<g1, 256, 0, stream>>>(x, la, ldt, lg, th, bl, out);
  wlm_k2<<<dim3(N_B * T_SEQ), 256, 0, stream>>>(out, lnw, lnb);
}

// Round 3
// 105.406 us; speedup vs baseline: 1.0834x; 1.0834x over previous
//
#include <hip/hip_runtime.h>
#include <cstdint>

#define T_SEQ 4096
#define E_DIM 1024
#define N_B   8
#define SC    128      // seq positions per block
#define TILE_P 148     // s0-10 .. s0+137
#define LDS_ST 149     // odd stride -> conflict-free scalar reads

constexpr int LW[4] = {2, 8, 12, 6};

// dec_lo
constexpr float DLf[4][12] = {
  {0.7071067811865476f, 0.7071067811865476f, 0,0,0,0,0,0,0,0,0,0},
  {-0.010597401784997278f, 0.032883011666982945f, 0.030841381835986965f, -0.18703481171888114f,
   -0.02798376941698385f, 0.6308807679295904f, 0.7148465705525415f, 0.23037781330885523f, 0,0,0,0},
  {-0.007800708325034148f, 0.0017677118642428036f, 0.04472490177066578f, -0.021060292512300564f,
   -0.07263752278646252f, 0.3379294217276218f, 0.787641141030194f, 0.4910559419267466f,
   -0.048311742585633f, -0.11799011114819057f, 0.0034907120842174702f, 0.015404109327027373f},
  {-0.08838834764831845f, 0.08838834764831845f, 0.7071067811865476f, 0.7071067811865476f,
    0.08838834764831845f, -0.08838834764831845f, 0,0,0,0,0,0},
};
// dec_hi
constexpr float DHf[4][12] = {
  {-0.7071067811865476f, 0.7071067811865476f, 0,0,0,0,0,0,0,0,0,0},
  {-0.23037781330885523f, 0.7148465705525415f, -0.6308807679295904f, -0.02798376941698385f,
    0.18703481171888114f, 0.030841381835986965f, -0.032883011666982945f, -0.010597401784997278f, 0,0,0,0},
  {-0.015404109327027373f, 0.0034907120842174702f, 0.11799011114819057f, -0.048311742585633f,
   -0.4910559419267466f, 0.787641141030194f, -0.3379294217276218f, -0.07263752278646252f,
    0.021060292512300564f, 0.04472490177066578f, -0.0017677118642428036f, -0.007800708325034148f},
  {0,0,-0.7071067811865476f, 0.7071067811865476f, 0,0, 0,0,0,0,0,0},
};
// rec_lo
constexpr float RLf[4][12] = {
  {0.7071067811865476f, 0.7071067811865476f, 0,0,0,0,0,0,0,0,0,0},
  {0.23037781330885523f, 0.7148465705525415f, 0.6308807679295904f, -0.02798376941698385f,
   -0.18703481171888114f, 0.030841381835986965f, 0.032883011666982945f, -0.010597401784997278f, 0,0,0,0},
  {0.015404109327027373f, 0.0034907120842174702f, -0.11799011114819057f, -0.048311742585633f,
   0.4910559419267466f, 0.787641141030194f, 0.3379294217276218f, -0.07263752278646252f,
   -0.021060292512300564f, 0.04472490177066578f, 0.0017677118642428036f, -0.007800708325034148f},
  {0,0,0.7071067811865476f, 0.7071067811865476f, 0,0, 0,0,0,0,0,0},
};
// rec_hi
constexpr float RHf[4][12] = {
  {0.7071067811865476f, -0.7071067811865476f, 0,0,0,0,0,0,0,0,0,0},
  {-0.010597401784997278f, -0.032883011666982945f, 0.030841381835986965f, 0.18703481171888114f,
   -0.02798376941698385f, -0.6308807679295904f, 0.7148465705525415f, -0.23037781330885523f, 0,0,0,0},
  {-0.007800708325034148f, -0.0017677118642428036f, 0.04472490177066578f, 0.021060292512300564f,
   -0.07263752278646252f, -0.3379294217276218f, 0.787641141030194f, -0.4910559419267466f,
   -0.048311742585633f, 0.11799011114819057f, 0.0034907120842174702f, -0.015404109327027373f},
  {-0.08838834764831845f, -0.08838834764831845f, 0.7071067811865476f, -0.7071067811865476f,
    0.08838834764831845f, 0.08838834764831845f, 0,0,0,0,0,0},
};

// soft-threshold * gain: (z - clamp(z,-lam,lam)) * gw  == gw*sign(z)*relu(|z|-lam)
__device__ __forceinline__ float shrink(float z, float lam, float nlam, float gw) {
  const float c = __builtin_amdgcn_fmed3f(z, nlam, lam);  // 1 VALU clamp
  return (z - c) * gw;
}

template <int W>
__device__ __forceinline__ void wavelet_accum(const float (&xw)[52], float (&acc)[32],
                                              float la, float nla, float ld, float nld,
                                              float gw) {
  constexpr int L  = LW[W];
  constexpr int KT = L / 2 + 15;
#pragma unroll
  for (int kk = 0; kk < KT; ++kk) {
    float lo = 0.f, hi = 0.f;
#pragma unroll
    for (int m = 0; m < L; ++m) {
      const float xv = xw[2 * kk + 11 - m];
      if (DLf[W][m] != 0.0f) lo += DLf[W][m] * xv;   // v_fmac_f32 lit-src0
      if (DHf[W][m] != 0.0f) hi += DHf[W][m] * xv;
    }
    const float loS = shrink(lo, la, nla, gw);
    const float hiS = shrink(hi, ld, nld, gw);
#pragma unroll
    for (int m = 0; m < L; ++m) {
      const int j = 2 * kk + m + 2 - L;   // compile-time after unroll
      if (j >= 0 && j < 32) {
        if (RLf[W][m] != 0.0f) acc[j] += loS * RLf[W][m];  // v_fmac_f32
        if (RHf[W][m] != 0.0f) acc[j] += hiS * RHf[W][m];
      }
    }
  }
}

__global__ __launch_bounds__(256, 4) void wlm_k1(
    const float* __restrict__ x,
    const float* __restrict__ la_, const float* __restrict__ ld_,
    const float* __restrict__ lg_, const float* __restrict__ th_,
    const float* __restrict__ bl_, float* __restrict__ y) {
  __shared__ float xs[64][LDS_ST];  // 38,144 B -> 4 blocks/CU (LDS-limited)

  const int tid  = threadIdx.x;
  const int lane = tid & 63;
  const int wave = tid >> 6;
  const int s0 = blockIdx.x * SC;
  const int e0 = blockIdx.y * 64;
  const int b  = blockIdx.z;

  // ---- stage x tile [s0-10, s0+138) x 64 channels, reflect at borders ----
  {
    const int ch4 = (tid & 15) * 4;
#pragma unroll
    for (int it = 0; it < 10; ++it) {
      const int pos = (tid >> 4) + it * 16;
      if (pos < TILE_P) {
        int g = s0 - 10 + pos;
        g = (g < 0) ? -g : g;
        g = (g >= T_SEQ) ? (2 * T_SEQ - 2 - g) : g;
        const float4 v = *reinterpret_cast<const float4*>(
            &x[((size_t)b * T_SEQ + g) * E_DIM + e0 + ch4]);
        xs[ch4 + 0][pos] = v.x;
        xs[ch4 + 1][pos] = v.y;
        xs[ch4 + 2][pos] = v.z;
        xs[ch4 + 3][pos] = v.w;
      }
    }
  }

  // ---- per-channel params ----
  const int e = e0 + lane;
  const float la = la_[e];
  const float ld = ld_[e];
  const float lg = lg_[e];
  const float th = th_[e];
  const float sp = fmaxf(lg, 0.f) + log1pf(expf(-fabsf(lg)));  // softplus
  const float g2 = (sp + 1e-6f) * cosf(th);
  const float nla = -la, nld = -ld;

  const float b0 = bl_[0], b1 = bl_[1], b2 = bl_[2], b3 = bl_[3];
  const float mx = fmaxf(fmaxf(b0, b1), fmaxf(b2, b3));
  float w0 = expf(b0 - mx), w1 = expf(b1 - mx), w2 = expf(b2 - mx), w3 = expf(b3 - mx);
  const float wrcp = 1.f / (w0 + w1 + w2 + w3);
  // fold softmax weight into the per-wavelet shrink gain
  const float g0 = g2 * w0 * wrcp, g1 = g2 * w1 * wrcp,
              g3 = g2 * w2 * wrcp, g4 = g2 * w3 * wrcp;

  __syncthreads();

  // ---- per-thread register window: x_ref[sA-10 .. sA+41] ----
  float xw[52];
#pragma unroll
  for (int i = 0; i < 52; ++i) xw[i] = xs[lane][wave * 32 + i];

  float acc[32];
#pragma unroll
  for (int j = 0; j < 32; ++j) acc[j] = 0.f;

  wavelet_accum<0>(xw, acc, la, nla, ld, nld, g0);
  wavelet_accum<1>(xw, acc, la, nla, ld, nld, g1);
  wavelet_accum<2>(xw, acc, la, nla, ld, nld, g3);
  wavelet_accum<3>(xw, acc, la, nla, ld, nld, g4);

  // ---- y = x + sum_i w_i * rec_i ----
  const int sA = s0 + wave * 32;
#pragma unroll
  for (int j = 0; j < 32; ++j) {
    y[((size_t)b * T_SEQ + sA + j) * E_DIM + e] = xw[j + 10] + acc[j];
  }
}

__global__ __launch_bounds__(256) void wlm_k2(float* __restrict__ y,
                                              const float* __restrict__ w,
                                              const float* __restrict__ bias) {
  const int token = blockIdx.x;
  const int tid = threadIdx.x;
  float* row = y + (size_t)token * E_DIM;

  float4 v = *reinterpret_cast<const float4*>(&row[tid * 4]);
  float s  = v.x + v.y + v.z + v.w;
  float sq = v.x * v.x + v.y * v.y + v.z * v.z + v.w * v.w;
#pragma unroll
  for (int off = 32; off; off >>= 1) {
    s  += __shfl_down(s, off);
    sq += __shfl_down(sq, off);
  }
  __shared__ float ps[4], pq[4], stat[2];
  const int wave = tid >> 6, lane = tid & 63;
  if (lane == 0) { ps[wave] = s; pq[wave] = sq; }
  __syncthreads();
  if (tid == 0) {
    const float S1 = ps[0] + ps[1] + ps[2] + ps[3];
    const float S2 = pq[0] + pq[1] + pq[2] + pq[3];
    const float mu = S1 * (1.f / E_DIM);
    const float var = S2 * (1.f / E_DIM) - mu * mu;
    stat[0] = mu;
    stat[1] = rsqrtf(var + 1e-5f);
  }
  __syncthreads();
  const float mu = stat[0], rstd = stat[1];
  const float4 wv = *reinterpret_cast<const float4*>(&w[tid * 4]);
  const float4 bv = *reinterpret_cast<const float4*>(&bias[tid * 4]);
  float4 o;
  o.x = (v.x - mu) * rstd * wv.x + bv.x;
  o.y = (v.y - mu) * rstd * wv.y + bv.y;
  o.z = (v.z - mu) * rstd * wv.z + bv.z;
  o.w = (v.w - mu) * rstd * wv.w + bv.w;
  *reinterpret_cast<float4*>(&row[tid * 4]) = o;
}

extern "C" void kernel_launch(void* const* d_in, const int* in_sizes, int n_in,
                              void* d_out, int out_size, void* d_ws, size_t ws_size,
                              hipStream_t stream) {
  const float* x   = (const float*)d_in[0];
  const float* la  = (const float*)d_in[1];
  const float* ldt = (const float*)d_in[2];
  const float* lg  = (const float*)d_in[3];
  const float* th  = (const float*)d_in[4];
  const float* bl  = (const float*)d_in[5];
  const float* lnw = (const float*)d_in[6];
  const float* lnb = (const float*)d_in[7];
  float* out = (float*)d_out;

  dim3 g1(T_SEQ / SC, E_DIM / 64, N_B);  // (32, 16, 8)
  wlm_k1<<<g1, 256, 0, stream>>>(x, la, ldt, lg, th, bl, out);
  wlm_k2<<<dim3(N_B * T_SEQ), 256, 0, stream>>>(out, lnw, lnb);
}